// Round 1
// baseline (117.292 us; speedup 1.0000x reference)
//
#include <hip/hip_runtime.h>
#include <math.h>

#define ALPHA 0.2f

// wa[0:F]   = W @ a1   (wa1[r] = sum_c W[r][c] * a[c])
// wa[F:2F]  = W @ a2   (wa2[r] = sum_c W[r][c] * a[F+c])
__global__ void wa_kernel(const float* __restrict__ W, const float* __restrict__ a,
                          float* __restrict__ wa, int F) {
    int wave = (int)((blockIdx.x * blockDim.x + threadIdx.x) >> 6);
    int lane = threadIdx.x & 63;
    if (wave >= F) return;
    const float* wr = W + (size_t)wave * F;
    float acc1 = 0.f, acc2 = 0.f;
    for (int c = lane; c < F; c += 64) {
        float w = wr[c];
        acc1 += w * a[c];
        acc2 += w * a[F + c];
    }
    #pragma unroll
    for (int off = 32; off; off >>= 1) {
        acc1 += __shfl_down(acc1, off);
        acc2 += __shfl_down(acc2, off);
    }
    if (lane == 0) { wa[wave] = acc1; wa[F + wave] = acc2; }
}

// out[r] = X[r] . v   — one wave per row, float4 loads
__global__ void rowdot_kernel(const float* __restrict__ X, const float* __restrict__ v,
                              float* __restrict__ out, int rows, int F) {
    int wave = (int)((blockIdx.x * blockDim.x + threadIdx.x) >> 6);
    int lane = threadIdx.x & 63;
    if (wave >= rows) return;
    const float4* xr = reinterpret_cast<const float4*>(X + (size_t)wave * F);
    const float4* vv = reinterpret_cast<const float4*>(v);
    float acc = 0.f;
    int F4 = F >> 2;
    for (int c = lane; c < F4; c += 64) {
        float4 x = xr[c];
        float4 y = vv[c];
        acc += x.x * y.x + x.y * y.y + x.z * y.z + x.w * y.w;
    }
    #pragma unroll
    for (int off = 32; off; off >>= 1) acc += __shfl_down(acc, off);
    if (lane == 0) out[wave] = acc;
}

// Per output row i: dedup neighbor indices, leaky-relu scores, softmax over
// distinct neighbors, then agg[i] = sum_k attn_k * embed[idx_k].
__global__ void aggregate_kernel(const float* __restrict__ embed, const int* __restrict__ nidx,
                                 const float* __restrict__ s1, const float* __restrict__ s2,
                                 float* __restrict__ agg, int M, int F, int K) {
    int i = blockIdx.x;
    // every thread computes the (tiny) softmax redundantly
    int idx[16];
    float e[16];
    int cnt = 0;
    for (int k = 0; k < K; k++) {
        int id = nidx[(size_t)i * K + k];
        bool dup = false;
        for (int p = 0; p < cnt; p++) dup |= (idx[p] == id);
        if (!dup) idx[cnt++] = id;
    }
    float s1i = s1[i];
    float m = -INFINITY;
    for (int p = 0; p < cnt; p++) {
        float v = s1i + s2[idx[p]];
        v = v > 0.f ? v : ALPHA * v;
        e[p] = v;
        m = fmaxf(m, v);
    }
    float sum = 0.f;
    for (int p = 0; p < cnt; p++) { e[p] = expf(e[p] - m); sum += e[p]; }
    float inv = 1.0f / sum;
    for (int p = 0; p < cnt; p++) e[p] *= inv;

    for (int f = threadIdx.x; f < F; f += blockDim.x) {
        float acc = 0.f;
        for (int p = 0; p < cnt; p++)
            acc += e[p] * embed[(size_t)idx[p] * F + f];
        agg[(size_t)i * F + f] = acc;
    }
}

// C[M x N] = A[M x K] @ B[K x N], fp32, 64x64 tile, 4x4 per thread
__global__ void gemm_f32_kernel(const float* __restrict__ A, const float* __restrict__ B,
                                float* __restrict__ C, int M, int N, int K) {
    __shared__ float As[16][64];   // [k][m]
    __shared__ float Bs[16][64];   // [k][n]
    int tx = threadIdx.x, ty = threadIdx.y;
    int tid = ty * 16 + tx;
    int m0 = blockIdx.y * 64, n0 = blockIdx.x * 64;

    float acc[4][4] = {};
    for (int k0 = 0; k0 < K; k0 += 16) {
        {   // A tile 64x16 -> As[k][m], each thread loads float4 along k
            int li = tid * 4;
            int am = li >> 4;        // 0..63
            int ak = li & 15;        // 0,4,8,12
            float4 av = *reinterpret_cast<const float4*>(&A[(size_t)(m0 + am) * K + k0 + ak]);
            As[ak + 0][am] = av.x;
            As[ak + 1][am] = av.y;
            As[ak + 2][am] = av.z;
            As[ak + 3][am] = av.w;
        }
        {   // B tile 16x64 -> Bs[k][n]
            int li = tid * 4;
            int bk = li >> 6;        // 0..15
            int bn = li & 63;        // multiple of 4
            *reinterpret_cast<float4*>(&Bs[bk][bn]) =
                *reinterpret_cast<const float4*>(&B[(size_t)(k0 + bk) * N + n0 + bn]);
        }
        __syncthreads();
        #pragma unroll
        for (int k = 0; k < 16; k++) {
            float4 a = *reinterpret_cast<const float4*>(&As[k][ty * 4]);
            float4 b = *reinterpret_cast<const float4*>(&Bs[k][tx * 4]);
            float ar[4] = {a.x, a.y, a.z, a.w};
            float br[4] = {b.x, b.y, b.z, b.w};
            #pragma unroll
            for (int ii = 0; ii < 4; ii++)
                #pragma unroll
                for (int jj = 0; jj < 4; jj++)
                    acc[ii][jj] += ar[ii] * br[jj];
        }
        __syncthreads();
    }
    #pragma unroll
    for (int ii = 0; ii < 4; ii++) {
        float4 st = make_float4(acc[ii][0], acc[ii][1], acc[ii][2], acc[ii][3]);
        *reinterpret_cast<float4*>(&C[(size_t)(m0 + ty * 4 + ii) * N + n0 + tx * 4]) = st;
    }
}

extern "C" void kernel_launch(void* const* d_in, const int* in_sizes, int n_in,
                              void* d_out, int out_size, void* d_ws, size_t ws_size,
                              hipStream_t stream) {
    const float* feat  = (const float*)d_in[0];
    const float* embed = (const float*)d_in[1];
    const float* W     = (const float*)d_in[2];
    const float* a     = (const float*)d_in[3];
    const int*   nidx  = (const int*)d_in[4];

    int F = in_sizes[3] / 2;          // 1024
    int N = in_sizes[0] / F;          // 2048
    int M = in_sizes[1] / F;          // 8192
    int K = in_sizes[4] / N;          // 10

    float* ws  = (float*)d_ws;
    float* wa  = ws;                   // 2F
    float* s1  = wa + 2 * F;           // N
    float* s2  = s1 + N;               // M
    float* agg = s2 + M;               // N*F

    // wa = W @ [a1, a2] : one wave per row
    {
        int waves = F;
        int blocks = (waves * 64 + 255) / 256;
        wa_kernel<<<blocks, 256, 0, stream>>>(W, a, wa, F);
    }
    // s1 = feat . wa1
    {
        int blocks = (N * 64 + 255) / 256;
        rowdot_kernel<<<blocks, 256, 0, stream>>>(feat, wa, s1, N, F);
    }
    // s2 = embed . wa2
    {
        int blocks = (M * 64 + 255) / 256;
        rowdot_kernel<<<blocks, 256, 0, stream>>>(embed, wa + F, s2, M, F);
    }
    // agg = softmax-gather
    aggregate_kernel<<<N, 256, 0, stream>>>(embed, nidx, s1, s2, agg, M, F, K);
    // out = agg @ W
    {
        dim3 grid(F / 64, N / 64);
        dim3 block(16, 16);
        gemm_f32_kernel<<<grid, block, 0, stream>>>(agg, W, (float*)d_out, N, F, F);
    }
}

// Round 2
// 71.080 us; speedup vs baseline: 1.6501x; 1.6501x over previous
//
#include <hip/hip_runtime.h>
#include <math.h>

#define ALPHA 0.2f

typedef _Float16 half8 __attribute__((ext_vector_type(8)));
typedef float f32x4 __attribute__((ext_vector_type(4)));

// wa[0:F]   = W @ a1 ; wa[F:2F] = W @ a2
__global__ void wa_kernel(const float* __restrict__ W, const float* __restrict__ a,
                          float* __restrict__ wa, int F) {
    int wave = (int)((blockIdx.x * blockDim.x + threadIdx.x) >> 6);
    int lane = threadIdx.x & 63;
    if (wave >= F) return;
    const float* wr = W + (size_t)wave * F;
    float acc1 = 0.f, acc2 = 0.f;
    for (int c = lane; c < F; c += 64) {
        float w = wr[c];
        acc1 += w * a[c];
        acc2 += w * a[F + c];
    }
    #pragma unroll
    for (int off = 32; off; off >>= 1) {
        acc1 += __shfl_down(acc1, off);
        acc2 += __shfl_down(acc2, off);
    }
    if (lane == 0) { wa[wave] = acc1; wa[F + wave] = acc2; }
}

// out[r] = X[r] . v   — one wave per row, float4 loads
__global__ void rowdot_kernel(const float* __restrict__ X, const float* __restrict__ v,
                              float* __restrict__ out, int rows, int F) {
    int wave = (int)((blockIdx.x * blockDim.x + threadIdx.x) >> 6);
    int lane = threadIdx.x & 63;
    if (wave >= rows) return;
    const float4* xr = reinterpret_cast<const float4*>(X + (size_t)wave * F);
    const float4* vv = reinterpret_cast<const float4*>(v);
    float acc = 0.f;
    int F4 = F >> 2;
    for (int c = lane; c < F4; c += 64) {
        float4 x = xr[c];
        float4 y = vv[c];
        acc += x.x * y.x + x.y * y.y + x.z * y.z + x.w * y.w;
    }
    #pragma unroll
    for (int off = 32; off; off >>= 1) acc += __shfl_down(acc, off);
    if (lane == 0) out[wave] = acc;
}

// Wt[n][k] = (fp16) W[k][n]  — 32x32 LDS transpose tiles
__global__ void wt_kernel(const float* __restrict__ W, _Float16* __restrict__ Wt, int F) {
    __shared__ float t[32][33];
    int bx = blockIdx.x * 32;   // k base
    int by = blockIdx.y * 32;   // n base
    int x = threadIdx.x;
    for (int i = threadIdx.y; i < 32; i += 8)
        t[i][x] = W[(size_t)(bx + i) * F + by + x];
    __syncthreads();
    for (int i = threadIdx.y; i < 32; i += 8)
        Wt[(size_t)(by + i) * F + bx + x] = (_Float16)t[x][i];
}

// Per output row i: dedup neighbors, leaky-relu scores, softmax, gather-blend.
// Writes agg in fp16 (GEMM A-operand).
__global__ void aggregate_kernel(const float* __restrict__ embed, const int* __restrict__ nidx,
                                 const float* __restrict__ s1, const float* __restrict__ s2,
                                 _Float16* __restrict__ agg, int M, int F, int K) {
    int i = blockIdx.x;
    int idx[16];
    float e[16];
    int cnt = 0;
    for (int k = 0; k < K; k++) {
        int id = nidx[(size_t)i * K + k];
        bool dup = false;
        for (int p = 0; p < cnt; p++) dup |= (idx[p] == id);
        if (!dup) idx[cnt++] = id;
    }
    float s1i = s1[i];
    float m = -INFINITY;
    for (int p = 0; p < cnt; p++) {
        float v = s1i + s2[idx[p]];
        v = v > 0.f ? v : ALPHA * v;
        e[p] = v;
        m = fmaxf(m, v);
    }
    float sum = 0.f;
    for (int p = 0; p < cnt; p++) { e[p] = expf(e[p] - m); sum += e[p]; }
    float inv = 1.0f / sum;
    for (int p = 0; p < cnt; p++) e[p] *= inv;

    for (int f = threadIdx.x; f < F; f += blockDim.x) {
        float acc = 0.f;
        for (int p = 0; p < cnt; p++)
            acc += e[p] * embed[(size_t)idx[p] * F + f];
        agg[(size_t)i * F + f] = (_Float16)acc;
    }
}

// C[M x N] = A[M x K] @ Bt[N x K]^T   (fp16 in, fp32 out, MFMA 16x16x32)
// 128x64 tile, 4 waves (2m x 2n), each wave 64x32; BK=32; reg-prefetch dbuf.
__global__ __launch_bounds__(256) void gemm_f16_kernel(
    const _Float16* __restrict__ A, const _Float16* __restrict__ Bt,
    float* __restrict__ C, int M, int N, int K) {
    __shared__ _Float16 As[128 * 40];   // row stride 40 fp16 = 80B (bank-friendly, 16B aligned)
    __shared__ _Float16 Bs[64 * 40];
    const int tid = threadIdx.x;
    const int m0 = blockIdx.y * 128;
    const int n0 = blockIdx.x * 64;
    const int l = tid & 63, w = tid >> 6;
    const int wm = w >> 1, wn = w & 1;
    const int lrow = l & 15, kc = l >> 4;

    f32x4 acc[4][2] = {};
    const int nt = K / 32;

    half8 arg0, arg1, brg;
    {   // prologue: tile 0 -> regs -> LDS
        int u0 = tid, u1 = tid + 256;
        arg0 = *(const half8*)&A[(size_t)(m0 + (u0 >> 2)) * K + (u0 & 3) * 8];
        arg1 = *(const half8*)&A[(size_t)(m0 + (u1 >> 2)) * K + (u1 & 3) * 8];
        brg  = *(const half8*)&Bt[(size_t)(n0 + (tid >> 2)) * K + (tid & 3) * 8];
        *(half8*)&As[(u0 >> 2) * 40 + (u0 & 3) * 8] = arg0;
        *(half8*)&As[(u1 >> 2) * 40 + (u1 & 3) * 8] = arg1;
        *(half8*)&Bs[(tid >> 2) * 40 + (tid & 3) * 8] = brg;
    }
    __syncthreads();

    for (int t = 0; t < nt; t++) {
        if (t + 1 < nt) {   // prefetch next tile into regs (no LDS hazard)
            int k0 = (t + 1) * 32;
            int u0 = tid, u1 = tid + 256;
            arg0 = *(const half8*)&A[(size_t)(m0 + (u0 >> 2)) * K + k0 + (u0 & 3) * 8];
            arg1 = *(const half8*)&A[(size_t)(m0 + (u1 >> 2)) * K + k0 + (u1 & 3) * 8];
            brg  = *(const half8*)&Bt[(size_t)(n0 + (tid >> 2)) * K + k0 + (tid & 3) * 8];
        }
        half8 av[4], bv[2];
        #pragma unroll
        for (int fm = 0; fm < 4; fm++)
            av[fm] = *(const half8*)&As[(wm * 64 + fm * 16 + lrow) * 40 + kc * 8];
        #pragma unroll
        for (int fn = 0; fn < 2; fn++)
            bv[fn] = *(const half8*)&Bs[(wn * 32 + fn * 16 + lrow) * 40 + kc * 8];
        #pragma unroll
        for (int fm = 0; fm < 4; fm++)
            #pragma unroll
            for (int fn = 0; fn < 2; fn++)
                acc[fm][fn] = __builtin_amdgcn_mfma_f32_16x16x32_f16(av[fm], bv[fn], acc[fm][fn], 0, 0, 0);
        __syncthreads();
        if (t + 1 < nt) {
            int u0 = tid, u1 = tid + 256;
            *(half8*)&As[(u0 >> 2) * 40 + (u0 & 3) * 8] = arg0;
            *(half8*)&As[(u1 >> 2) * 40 + (u1 & 3) * 8] = arg1;
            *(half8*)&Bs[(tid >> 2) * 40 + (tid & 3) * 8] = brg;
            __syncthreads();
        }
    }
    // epilogue: C/D layout col = lane&15, row = (lane>>4)*4 + r
    #pragma unroll
    for (int fm = 0; fm < 4; fm++)
        #pragma unroll
        for (int fn = 0; fn < 2; fn++)
            #pragma unroll
            for (int r = 0; r < 4; r++)
                C[(size_t)(m0 + wm * 64 + fm * 16 + kc * 4 + r) * N
                  + n0 + wn * 32 + fn * 16 + lrow] = acc[fm][fn][r];
}

extern "C" void kernel_launch(void* const* d_in, const int* in_sizes, int n_in,
                              void* d_out, int out_size, void* d_ws, size_t ws_size,
                              hipStream_t stream) {
    const float* feat  = (const float*)d_in[0];
    const float* embed = (const float*)d_in[1];
    const float* W     = (const float*)d_in[2];
    const float* a     = (const float*)d_in[3];
    const int*   nidx  = (const int*)d_in[4];

    int F = in_sizes[3] / 2;          // 1024
    int N = in_sizes[0] / F;          // 2048
    int M = in_sizes[1] / F;          // 8192
    int K = in_sizes[4] / N;          // 10

    float* ws  = (float*)d_ws;
    float* wa  = ws;                           // 2F floats
    float* s1  = wa + 2 * F;                   // N
    float* s2  = s1 + N;                       // M
    _Float16* agg_f16 = (_Float16*)(s2 + M);   // N*F halfs (16B-aligned)
    _Float16* wt_f16  = agg_f16 + (size_t)N * F; // F*F halfs

    // wa = W @ [a1, a2]
    wa_kernel<<<(F * 64 + 255) / 256, 256, 0, stream>>>(W, a, wa, F);
    // s1 = feat . wa1 ; s2 = embed . wa2
    rowdot_kernel<<<(N * 64 + 255) / 256, 256, 0, stream>>>(feat, wa, s1, N, F);
    rowdot_kernel<<<(M * 64 + 255) / 256, 256, 0, stream>>>(embed, wa + F, s2, M, F);
    // Wt = W^T (fp16)
    {
        dim3 grid(F / 32, F / 32), block(32, 8);
        wt_kernel<<<grid, block, 0, stream>>>(W, wt_f16, F);
    }
    // agg = softmax-gather (fp16 out)
    aggregate_kernel<<<N, 256, 0, stream>>>(embed, nidx, s1, s2, agg_f16, M, F, K);
    // out = agg @ W  via MFMA (A=[N][F] fp16, Bt=[F][F] fp16 = W^T)
    {
        dim3 grid(F / 64, N / 128);
        gemm_f16_kernel<<<grid, 256, 0, stream>>>(agg_f16, wt_f16, (float*)d_out, N, F, F);
    }
}

// Round 3
// 48.904 us; speedup vs baseline: 2.3984x; 1.4535x over previous
//
#include <hip/hip_runtime.h>
#include <math.h>

#define ALPHA 0.2f
#define MAXK 10

typedef _Float16 half8 __attribute__((ext_vector_type(8)));
typedef _Float16 half4 __attribute__((ext_vector_type(4)));
typedef float f32x4 __attribute__((ext_vector_type(4)));

// wa[0:F] = W @ a1 ; wa[F:2F] = W @ a2  — one wave per row of W
__global__ void wa_kernel(const float* __restrict__ W, const float* __restrict__ a,
                          float* __restrict__ wa, int F) {
    int wave = (int)((blockIdx.x * blockDim.x + threadIdx.x) >> 6);
    int lane = threadIdx.x & 63;
    if (wave >= F) return;
    const float* wr = W + (size_t)wave * F;
    float acc1 = 0.f, acc2 = 0.f;
    for (int c = lane; c < F; c += 64) {
        float w = wr[c];
        acc1 += w * a[c];
        acc2 += w * a[F + c];
    }
    #pragma unroll
    for (int off = 32; off; off >>= 1) {
        acc1 += __shfl_down(acc1, off);
        acc2 += __shfl_down(acc2, off);
    }
    if (lane == 0) { wa[wave] = acc1; wa[F + wave] = acc2; }
}

// Wt[n][k] = (fp16) W[k][n]  — 32x32 LDS transpose tiles
__global__ void wt_kernel(const float* __restrict__ W, _Float16* __restrict__ Wt, int F) {
    __shared__ float t[32][33];
    int bx = blockIdx.x * 32;   // k base
    int by = blockIdx.y * 32;   // n base
    int x = threadIdx.x;
    for (int i = threadIdx.y; i < 32; i += 8)
        t[i][x] = W[(size_t)(bx + i) * F + by + x];
    __syncthreads();
    for (int i = threadIdx.y; i < 32; i += 8)
        Wt[(size_t)(by + i) * F + bx + x] = (_Float16)t[x][i];
}

// Fused: s1 = feat[i].wa1, s2[k] = embed[idx_k].wa2 (computed from the gathered
// rows), leaky-relu + dedup-masked softmax, blend from register-resident rows.
// One block per output row; thread t owns float4 chunk f = 4t (F=1024, 256 thr).
__global__ __launch_bounds__(256) void aggregate_fused_kernel(
    const float* __restrict__ feat, const float* __restrict__ embed,
    const int* __restrict__ nidx, const float* __restrict__ wa,
    _Float16* __restrict__ agg, int F) {
    const int i = blockIdx.x;
    const int tid = threadIdx.x;
    const int f = tid * 4;

    // neighbor indices + duplicate flags (uniform across the block)
    int idx[MAXK];
    bool dup[MAXK];
    #pragma unroll
    for (int k = 0; k < MAXK; k++) idx[k] = nidx[i * MAXK + k];
    #pragma unroll
    for (int k = 0; k < MAXK; k++) {
        bool d = false;
        #pragma unroll
        for (int p = 0; p < MAXK; p++)
            if (p < k) d |= (idx[p] == idx[k]);
        dup[k] = d;
    }

    float4 wa1 = *(const float4*)&wa[f];
    float4 wa2 = *(const float4*)&wa[F + f];
    float4 fv  = *(const float4*)&feat[(size_t)i * F + f];
    float a1p = fv.x * wa1.x + fv.y * wa1.y + fv.z * wa1.z + fv.w * wa1.w;

    float4 rv[MAXK];          // register-resident row chunks
    float a2p[MAXK];
    #pragma unroll
    for (int k = 0; k < MAXK; k++) {
        rv[k] = *(const float4*)&embed[(size_t)idx[k] * F + f];
        a2p[k] = rv[k].x * wa2.x + rv[k].y * wa2.y + rv[k].z * wa2.z + rv[k].w * wa2.w;
    }

    // block-reduce the 11 partials (wave shfl tree + 4-wave LDS combine)
    #pragma unroll
    for (int off = 32; off; off >>= 1) {
        a1p += __shfl_down(a1p, off);
        #pragma unroll
        for (int k = 0; k < MAXK; k++) a2p[k] += __shfl_down(a2p[k], off);
    }
    __shared__ float red[MAXK + 1][4];
    const int w = tid >> 6, l = tid & 63;
    if (l == 0) {
        red[0][w] = a1p;
        #pragma unroll
        for (int k = 0; k < MAXK; k++) red[k + 1][w] = a2p[k];
    }
    __syncthreads();

    float s1 = red[0][0] + red[0][1] + red[0][2] + red[0][3];
    float sc[MAXK];
    float m = -INFINITY;
    #pragma unroll
    for (int k = 0; k < MAXK; k++) {
        float v = s1 + red[k + 1][0] + red[k + 1][1] + red[k + 1][2] + red[k + 1][3];
        v = v > 0.f ? v : ALPHA * v;
        sc[k] = v;
        if (!dup[k]) m = fmaxf(m, v);
    }
    float sum = 0.f;
    #pragma unroll
    for (int k = 0; k < MAXK; k++) {
        sc[k] = dup[k] ? 0.f : expf(sc[k] - m);
        sum += sc[k];
    }
    float inv = 1.0f / sum;

    float4 o = make_float4(0.f, 0.f, 0.f, 0.f);
    #pragma unroll
    for (int k = 0; k < MAXK; k++) {
        float wk = sc[k] * inv;
        o.x += wk * rv[k].x;
        o.y += wk * rv[k].y;
        o.z += wk * rv[k].z;
        o.w += wk * rv[k].w;
    }
    half4 h = { (_Float16)o.x, (_Float16)o.y, (_Float16)o.z, (_Float16)o.w };
    *(half4*)&agg[(size_t)i * F + f] = h;
}

// C[M x N] = A[M x K] @ Bt[N x K]^T   (fp16 in, fp32 out, MFMA 16x16x32)
// 128x64 tile, 4 waves (2m x 2n), each wave 64x32; BK=32; reg-prefetch dbuf.
__global__ __launch_bounds__(256) void gemm_f16_kernel(
    const _Float16* __restrict__ A, const _Float16* __restrict__ Bt,
    float* __restrict__ C, int M, int N, int K) {
    __shared__ _Float16 As[128 * 40];   // row stride 40 halfs = 80B
    __shared__ _Float16 Bs[64 * 40];
    const int tid = threadIdx.x;
    const int m0 = blockIdx.y * 128;
    const int n0 = blockIdx.x * 64;
    const int l = tid & 63, w = tid >> 6;
    const int wm = w >> 1, wn = w & 1;
    const int lrow = l & 15, kc = l >> 4;

    f32x4 acc[4][2] = {};
    const int nt = K / 32;

    half8 arg0, arg1, brg;
    {   // prologue: tile 0 -> regs -> LDS
        int u0 = tid, u1 = tid + 256;
        arg0 = *(const half8*)&A[(size_t)(m0 + (u0 >> 2)) * K + (u0 & 3) * 8];
        arg1 = *(const half8*)&A[(size_t)(m0 + (u1 >> 2)) * K + (u1 & 3) * 8];
        brg  = *(const half8*)&Bt[(size_t)(n0 + (tid >> 2)) * K + (tid & 3) * 8];
        *(half8*)&As[(u0 >> 2) * 40 + (u0 & 3) * 8] = arg0;
        *(half8*)&As[(u1 >> 2) * 40 + (u1 & 3) * 8] = arg1;
        *(half8*)&Bs[(tid >> 2) * 40 + (tid & 3) * 8] = brg;
    }
    __syncthreads();

    for (int t = 0; t < nt; t++) {
        if (t + 1 < nt) {   // prefetch next tile into regs
            int k0 = (t + 1) * 32;
            int u0 = tid, u1 = tid + 256;
            arg0 = *(const half8*)&A[(size_t)(m0 + (u0 >> 2)) * K + k0 + (u0 & 3) * 8];
            arg1 = *(const half8*)&A[(size_t)(m0 + (u1 >> 2)) * K + k0 + (u1 & 3) * 8];
            brg  = *(const half8*)&Bt[(size_t)(n0 + (tid >> 2)) * K + k0 + (tid & 3) * 8];
        }
        half8 av[4], bv[2];
        #pragma unroll
        for (int fm = 0; fm < 4; fm++)
            av[fm] = *(const half8*)&As[(wm * 64 + fm * 16 + lrow) * 40 + kc * 8];
        #pragma unroll
        for (int fn = 0; fn < 2; fn++)
            bv[fn] = *(const half8*)&Bs[(wn * 32 + fn * 16 + lrow) * 40 + kc * 8];
        #pragma unroll
        for (int fm = 0; fm < 4; fm++)
            #pragma unroll
            for (int fn = 0; fn < 2; fn++)
                acc[fm][fn] = __builtin_amdgcn_mfma_f32_16x16x32_f16(av[fm], bv[fn], acc[fm][fn], 0, 0, 0);
        __syncthreads();
        if (t + 1 < nt) {
            int u0 = tid, u1 = tid + 256;
            *(half8*)&As[(u0 >> 2) * 40 + (u0 & 3) * 8] = arg0;
            *(half8*)&As[(u1 >> 2) * 40 + (u1 & 3) * 8] = arg1;
            *(half8*)&Bs[(tid >> 2) * 40 + (tid & 3) * 8] = brg;
            __syncthreads();
        }
    }
    // epilogue: C/D layout col = lane&15, row = (lane>>4)*4 + r
    #pragma unroll
    for (int fm = 0; fm < 4; fm++)
        #pragma unroll
        for (int fn = 0; fn < 2; fn++)
            #pragma unroll
            for (int r = 0; r < 4; r++)
                C[(size_t)(m0 + wm * 64 + fm * 16 + kc * 4 + r) * N
                  + n0 + wn * 32 + fn * 16 + lrow] = acc[fm][fn][r];
}

extern "C" void kernel_launch(void* const* d_in, const int* in_sizes, int n_in,
                              void* d_out, int out_size, void* d_ws, size_t ws_size,
                              hipStream_t stream) {
    const float* feat  = (const float*)d_in[0];
    const float* embed = (const float*)d_in[1];
    const float* W     = (const float*)d_in[2];
    const float* a     = (const float*)d_in[3];
    const int*   nidx  = (const int*)d_in[4];

    int F = in_sizes[3] / 2;          // 1024
    int N = in_sizes[0] / F;          // 2048
    int M = in_sizes[1] / F;          // 8192

    float* ws = (float*)d_ws;
    float* wa = ws;                                 // 2F floats
    _Float16* agg_f16 = (_Float16*)(wa + 2 * F);    // N*F halfs
    _Float16* wt_f16  = agg_f16 + (size_t)N * F;    // F*F halfs
    (void)M;

    // wa = W @ [a1, a2]
    wa_kernel<<<(F * 64 + 255) / 256, 256, 0, stream>>>(W, a, wa, F);
    // Wt = W^T (fp16)
    {
        dim3 grid(F / 32, F / 32), block(32, 8);
        wt_kernel<<<grid, block, 0, stream>>>(W, wt_f16, F);
    }
    // fused scores + softmax + gather-blend (fp16 out)
    aggregate_fused_kernel<<<N, 256, 0, stream>>>(feat, embed, nidx, wa, agg_f16, F);
    // out = agg @ W via MFMA (A=[N][F] fp16, Bt=[F][F] fp16 = W^T)
    {
        dim3 grid(F / 64, N / 128);
        gemm_f16_kernel<<<grid, 256, 0, stream>>>(agg_f16, wt_f16, (float*)d_out, N, F, F);
    }
}

// Round 4
// 41.408 us; speedup vs baseline: 2.8326x; 1.1810x over previous
//
#include <hip/hip_runtime.h>
#include <math.h>

#define ALPHA 0.2f
#define MAXK 10

typedef _Float16 half8 __attribute__((ext_vector_type(8)));
typedef _Float16 half4 __attribute__((ext_vector_type(4)));
typedef float f32x4 __attribute__((ext_vector_type(4)));

__device__ __forceinline__ void gload_lds16(const void* g, void* l) {
    __builtin_amdgcn_global_load_lds(
        (const __attribute__((address_space(1))) unsigned int*)g,
        (__attribute__((address_space(3))) unsigned int*)l, 16, 0, 0);
}

// wa[0:F] = W @ a1 ; wa[F:2F] = W @ a2  — one wave per row of W, float4 loads
__global__ void wa_kernel(const float* __restrict__ W, const float* __restrict__ a,
                          float* __restrict__ wa, int F) {
    int wave = (int)((blockIdx.x * blockDim.x + threadIdx.x) >> 6);
    int lane = threadIdx.x & 63;
    if (wave >= F) return;
    const float4* wr = reinterpret_cast<const float4*>(W + (size_t)wave * F);
    const float4* a1 = reinterpret_cast<const float4*>(a);
    const float4* a2 = reinterpret_cast<const float4*>(a + F);
    float acc1 = 0.f, acc2 = 0.f;
    int F4 = F >> 2;
    for (int c = lane; c < F4; c += 64) {
        float4 w = wr[c];
        float4 x = a1[c];
        float4 y = a2[c];
        acc1 += w.x * x.x + w.y * x.y + w.z * x.z + w.w * x.w;
        acc2 += w.x * y.x + w.y * y.y + w.z * y.z + w.w * y.w;
    }
    #pragma unroll
    for (int off = 32; off; off >>= 1) {
        acc1 += __shfl_down(acc1, off);
        acc2 += __shfl_down(acc2, off);
    }
    if (lane == 0) { wa[wave] = acc1; wa[F + wave] = acc2; }
}

// Wt[n][k] = (fp16) W[k][n]  — 32x32 LDS transpose tiles
__global__ void wt_kernel(const float* __restrict__ W, _Float16* __restrict__ Wt, int F) {
    __shared__ float t[32][33];
    int bx = blockIdx.x * 32;   // k base
    int by = blockIdx.y * 32;   // n base
    int x = threadIdx.x;
    for (int i = threadIdx.y; i < 32; i += 8)
        t[i][x] = W[(size_t)(bx + i) * F + by + x];
    __syncthreads();
    for (int i = threadIdx.y; i < 32; i += 8)
        Wt[(size_t)(by + i) * F + bx + x] = (_Float16)t[x][i];
}

// Fused: scores + dedup-masked softmax + gather-blend; agg out in fp16.
// One block per output row; thread t owns float4 chunk f = 4t (F=1024).
__global__ __launch_bounds__(256) void aggregate_fused_kernel(
    const float* __restrict__ feat, const float* __restrict__ embed,
    const int* __restrict__ nidx, const float* __restrict__ wa,
    _Float16* __restrict__ agg, int F) {
    const int i = blockIdx.x;
    const int tid = threadIdx.x;
    const int f = tid * 4;

    int idx[MAXK];
    bool dup[MAXK];
    #pragma unroll
    for (int k = 0; k < MAXK; k++) idx[k] = nidx[i * MAXK + k];
    #pragma unroll
    for (int k = 0; k < MAXK; k++) {
        bool d = false;
        #pragma unroll
        for (int p = 0; p < MAXK; p++)
            if (p < k) d |= (idx[p] == idx[k]);
        dup[k] = d;
    }

    float4 wa1 = *(const float4*)&wa[f];
    float4 wa2 = *(const float4*)&wa[F + f];
    float4 fv  = *(const float4*)&feat[(size_t)i * F + f];
    float a1p = fv.x * wa1.x + fv.y * wa1.y + fv.z * wa1.z + fv.w * wa1.w;

    float4 rv[MAXK];
    float a2p[MAXK];
    #pragma unroll
    for (int k = 0; k < MAXK; k++) {
        rv[k] = *(const float4*)&embed[(size_t)idx[k] * F + f];
        a2p[k] = rv[k].x * wa2.x + rv[k].y * wa2.y + rv[k].z * wa2.z + rv[k].w * wa2.w;
    }

    #pragma unroll
    for (int off = 32; off; off >>= 1) {
        a1p += __shfl_down(a1p, off);
        #pragma unroll
        for (int k = 0; k < MAXK; k++) a2p[k] += __shfl_down(a2p[k], off);
    }
    __shared__ float red[MAXK + 1][4];
    const int w = tid >> 6, l = tid & 63;
    if (l == 0) {
        red[0][w] = a1p;
        #pragma unroll
        for (int k = 0; k < MAXK; k++) red[k + 1][w] = a2p[k];
    }
    __syncthreads();

    float s1 = red[0][0] + red[0][1] + red[0][2] + red[0][3];
    float sc[MAXK];
    float m = -INFINITY;
    #pragma unroll
    for (int k = 0; k < MAXK; k++) {
        float v = s1 + red[k + 1][0] + red[k + 1][1] + red[k + 1][2] + red[k + 1][3];
        v = v > 0.f ? v : ALPHA * v;
        sc[k] = v;
        if (!dup[k]) m = fmaxf(m, v);
    }
    float sum = 0.f;
    #pragma unroll
    for (int k = 0; k < MAXK; k++) {
        sc[k] = dup[k] ? 0.f : expf(sc[k] - m);
        sum += sc[k];
    }
    float inv = 1.0f / sum;

    float4 o = make_float4(0.f, 0.f, 0.f, 0.f);
    #pragma unroll
    for (int k = 0; k < MAXK; k++) {
        float wk = sc[k] * inv;
        o.x += wk * rv[k].x;
        o.y += wk * rv[k].y;
        o.z += wk * rv[k].z;
        o.w += wk * rv[k].w;
    }
    half4 h = { (_Float16)o.x, (_Float16)o.y, (_Float16)o.z, (_Float16)o.w };
    *(half4*)&agg[(size_t)i * F + f] = h;
}

// C[M x N] = A[M x K] @ Bt[N x K]^T  (fp16 in, fp32 out, mfma 16x16x32)
// 64x64 tile, BK=64, 4 waves (2m x 2n quadrants), double-buffered LDS,
// global_load_lds staging with inverse-swizzled source (rule 21):
//   LDS[row][slot] = SRC[row][slot ^ (row&7)]   (slot = 16B granule, 8/row)
// so reads use slot' = slot ^ (row&7)  ->  2-way (free) bank aliasing.
__global__ __launch_bounds__(256) void gemm_f16_kernel(
    const _Float16* __restrict__ A, const _Float16* __restrict__ Bt,
    float* __restrict__ C, int M, int N, int K) {
    __shared__ _Float16 As[2][64 * 64];
    __shared__ _Float16 Bs[2][64 * 64];
    const int tid = threadIdx.x;
    const int m0 = blockIdx.y * 64;
    const int n0 = blockIdx.x * 64;
    const int l = tid & 63, wv = tid >> 6;
    const int wm = wv >> 1, wn = wv & 1;
    const int lrow = l & 15, kc = l >> 4;           // frag row (col of C), k-chunk

    // staging geometry: lane l covers row (l>>3), granule (l&7) of a 8-row group
    const int srow = l >> 3;                        // 0..7 within row-group
    const int sslot = (l & 7) ^ (srow & 7);         // inverse-swizzled src granule
    const int nt = K >> 6;

    f32x4 acc[2][2] = {};

    // per-wave rowgroups: wv*2 and wv*2+1 (8 rows each -> 64 rows total)
    const int rg0 = wv * 2, rg1 = wv * 2 + 1;

    #define STAGE(buf, t)                                                          \
    do {                                                                           \
        int k0_ = (t) * 64;                                                        \
        gload_lds16(&A[(size_t)(m0 + rg0 * 8 + srow) * K + k0_ + sslot * 8],       \
                    (void*)((char*)&As[buf][0] + rg0 * 1024 + l * 16));            \
        gload_lds16(&A[(size_t)(m0 + rg1 * 8 + srow) * K + k0_ + sslot * 8],       \
                    (void*)((char*)&As[buf][0] + rg1 * 1024 + l * 16));            \
        gload_lds16(&Bt[(size_t)(n0 + rg0 * 8 + srow) * K + k0_ + sslot * 8],      \
                    (void*)((char*)&Bs[buf][0] + rg0 * 1024 + l * 16));            \
        gload_lds16(&Bt[(size_t)(n0 + rg1 * 8 + srow) * K + k0_ + sslot * 8],      \
                    (void*)((char*)&Bs[buf][0] + rg1 * 1024 + l * 16));            \
    } while (0)

    STAGE(0, 0);
    asm volatile("s_waitcnt vmcnt(0)" ::: "memory");
    __syncthreads();

    int buf = 0;
    for (int t = 0; t < nt; ++t) {
        if (t + 1 < nt) STAGE(buf ^ 1, t + 1);

        half8 av[2][2], bv[2][2];   // [ks][frag]
        #pragma unroll
        for (int ks = 0; ks < 2; ks++) {
            #pragma unroll
            for (int fq = 0; fq < 2; fq++) {
                int arow = wm * 32 + fq * 16 + lrow;
                int aslot = (ks * 4 + kc) ^ (arow & 7);
                av[ks][fq] = *(const half8*)((const char*)&As[buf][0] + arow * 128 + aslot * 16);
                int brow = wn * 32 + fq * 16 + lrow;
                int bslot = (ks * 4 + kc) ^ (brow & 7);
                bv[ks][fq] = *(const half8*)((const char*)&Bs[buf][0] + brow * 128 + bslot * 16);
            }
        }
        #pragma unroll
        for (int ks = 0; ks < 2; ks++)
            #pragma unroll
            for (int fq = 0; fq < 2; fq++)
                #pragma unroll
                for (int g = 0; g < 2; g++)
                    acc[fq][g] = __builtin_amdgcn_mfma_f32_16x16x32_f16(
                        av[ks][fq], bv[ks][g], acc[fq][g], 0, 0, 0);

        asm volatile("s_waitcnt vmcnt(0)" ::: "memory");
        __syncthreads();
        buf ^= 1;
    }
    #undef STAGE

    // C/D layout: col = lane&15 (=lrow), row = (lane>>4)*4 + r (=kc*4+r)
    #pragma unroll
    for (int fq = 0; fq < 2; fq++)
        #pragma unroll
        for (int g = 0; g < 2; g++)
            #pragma unroll
            for (int r = 0; r < 4; r++)
                C[(size_t)(m0 + wm * 32 + fq * 16 + kc * 4 + r) * N
                  + n0 + wn * 32 + g * 16 + lrow] = acc[fq][g][r];
}

extern "C" void kernel_launch(void* const* d_in, const int* in_sizes, int n_in,
                              void* d_out, int out_size, void* d_ws, size_t ws_size,
                              hipStream_t stream) {
    const float* feat  = (const float*)d_in[0];
    const float* embed = (const float*)d_in[1];
    const float* W     = (const float*)d_in[2];
    const float* a     = (const float*)d_in[3];
    const int*   nidx  = (const int*)d_in[4];

    int F = in_sizes[3] / 2;          // 1024
    int N = in_sizes[0] / F;          // 2048
    int M = in_sizes[1] / F;          // 8192

    float* ws = (float*)d_ws;
    float* wa = ws;                                 // 2F floats
    _Float16* agg_f16 = (_Float16*)(wa + 2 * F);    // N*F halfs
    _Float16* wt_f16  = agg_f16 + (size_t)N * F;    // F*F halfs
    (void)M;

    // wa = W @ [a1, a2]
    wa_kernel<<<(F * 64 + 255) / 256, 256, 0, stream>>>(W, a, wa, F);
    // Wt = W^T (fp16)
    {
        dim3 grid(F / 32, F / 32), block(32, 8);
        wt_kernel<<<grid, block, 0, stream>>>(W, wt_f16, F);
    }
    // fused scores + softmax + gather-blend (fp16 out)
    aggregate_fused_kernel<<<N, 256, 0, stream>>>(feat, embed, nidx, wa, agg_f16, F);
    // out = agg @ W via MFMA (A=[N][F] fp16, Bt=[F][F] fp16 = W^T)
    {
        dim3 grid(F / 64, N / 64);   // (16, 32) = 512 blocks
        gemm_f16_kernel<<<grid, 256, 0, stream>>>(agg_f16, wt_f16, (float*)d_out, N, F, F);
    }
}